// Round 5
// baseline (121.311 us; speedup 1.0000x reference)
//
#include <hip/hip_runtime.h>
#include <math.h>

#define BS_ 16
#define NQ_ 900
#define NC_ 91
#define NT_ 1600
#define NROWS_ (BS_ * NQ_)
#define TILE_R 4
#define TPB 320                  // 5 waves
#define NBLK (NROWS_ / TILE_R)   // 3600 blocks
#define KITER 5                  // 80 chunk-cols per k * 5 = 400 float4/row

typedef float f2 __attribute__((ext_vector_type(2)));

// Block = 4 query rows. Thread t owns row r = t&3 (static -> q consts in
// registers) and chunk c4 = (t>>2)+80k; writes ONE float4 per k (4 targets,
// one row) -> 5 dwordx4 stores/thread instead of 20 dword stores.
// Probs stored (2-p) in LDS as [id][4rows]; lane-quad gathers hit 4
// consecutive banks (conflict-free). Box loads are lane-quad-shared L1 hits.
__global__ __launch_bounds__(TPB) void matcher_cost_kernel(
    const float* __restrict__ logits,    // [NROWS_, NC_]
    const float4* __restrict__ pboxes,   // [NROWS_] cxcywh
    const float4* __restrict__ tboxes,   // [NT_] cxcywh
    const int4*  __restrict__ tids4,     // [NT_/4]
    float4* __restrict__ out4)           // [NROWS_ * NT_/4]
{
    const int base = blockIdx.x * TILE_R;
    const int tid  = threadIdx.x;
    const int lane = tid & 63;
    const int wave = tid >> 6;
    const int r    = tid & 3;        // fixed row within tile
    const int c4b  = tid >> 2;       // 0..79

    __shared__ __align__(16) float sneg[NC_ * TILE_R];  // (2 - p)[id][row]

    // ---- softmax: waves 0..3, one row each; wave 4 skips ----
    if (wave < TILE_R) {
        const float* lrow = logits + (base + wave) * NC_;
        float v0 = lrow[lane];
        float v1 = (lane < NC_ - 64) ? lrow[64 + lane] : -INFINITY;
        float m = fmaxf(v0, v1);
        #pragma unroll
        for (int off = 32; off >= 1; off >>= 1)
            m = fmaxf(m, __shfl_xor(m, off, 64));
        float e0 = __expf(v0 - m);
        float e1 = (lane < NC_ - 64) ? __expf(v1 - m) : 0.0f;
        float s = e0 + e1;
        #pragma unroll
        for (int off = 32; off >= 1; off >>= 1)
            s += __shfl_xor(s, off, 64);
        const float inv_s = __builtin_amdgcn_rcpf(s);
        sneg[lane * TILE_R + wave] = fmaf(-e0, inv_s, 2.0f);
        if (lane < NC_ - 64)
            sneg[(64 + lane) * TILE_R + wave] = fmaf(-e1, inv_s, 2.0f);
    }

    // ---- this thread's row constants (registers, static index) ----
    const float4 qb = pboxes[base + r];
    const f2 qc  = {qb.x, qb.y};
    const f2 qwh = {qb.z, qb.w};
    const f2 q0  = qc - 0.5f * qwh;
    const f2 q1  = qc + 0.5f * qwh;
    const float qarea = qb.z * qb.w;
    const int orow = (base + r) * (NT_ / 4);   // float4 units

    __syncthreads();

    #pragma unroll
    for (int k = 0; k < KITER; ++k) {
        const int c4 = c4b + 80 * k;
        const int j0 = c4 * 4;

        const int4 id4 = tids4[c4];
        const float4 b0 = tboxes[j0 + 0];
        const float4 b1 = tboxes[j0 + 1];
        const float4 b2 = tboxes[j0 + 2];
        const float4 b3 = tboxes[j0 + 3];

        const float p0 = sneg[id4.x * TILE_R + r];
        const float p1 = sneg[id4.y * TILE_R + r];
        const float p2 = sneg[id4.z * TILE_R + r];
        const float p3 = sneg[id4.w * TILE_R + r];

        float4 res;
        const float4 bb[4] = {b0, b1, b2, b3};
        const float  pp[4] = {p0, p1, p2, p3};
        float rr[4];
        #pragma unroll
        for (int i = 0; i < 4; ++i) {
            const float4 b = bb[i];
            const f2 tc  = {b.x, b.y};
            const f2 twh = {b.z, b.w};
            const f2 t0  = tc - 0.5f * twh;     // pk_fma
            const f2 t1  = tc + 0.5f * twh;
            const float ta = b.z * b.w;

            // L1 (cxcywh)
            const f2 dc  = qc - tc;
            const f2 dwh = qwh - twh;
            const float cb = (fabsf(dc.x) + fabsf(dc.y))
                           + (fabsf(dwh.x) + fabsf(dwh.y));

            // overlap extents (unclamped)
            const f2 mn = __builtin_elementwise_min(q1, t1);
            const f2 mx = __builtin_elementwise_max(q0, t0);
            const f2 d  = mn - mx;
            const f2 z  = __builtin_elementwise_max(d, (f2){0.0f, 0.0f});
            const float inter = z.x * z.y;
            const float uni   = (qarea + ta) - inter;

            // enclosing box: cwh = (qwh + twh) - d
            const f2 cwh = (qwh + twh) - d;
            const float areac = cwh.x * cwh.y;

            // C = 5*L1 + (2 - p) - 2*inter/uni - 2*uni/areac
            float c = fmaf(5.0f, cb, pp[i]);
            c = fmaf(-2.0f * inter, __builtin_amdgcn_rcpf(uni),   c);
            c = fmaf(-2.0f * uni,   __builtin_amdgcn_rcpf(areac), c);
            rr[i] = c;
        }
        res.x = rr[0]; res.y = rr[1]; res.z = rr[2]; res.w = rr[3];
        out4[orow + c4] = res;
    }
}

extern "C" void kernel_launch(void* const* d_in, const int* in_sizes, int n_in,
                              void* d_out, int out_size, void* d_ws, size_t ws_size,
                              hipStream_t stream) {
    const float*  logits = (const float*)d_in[0];   // [16,900,91]
    const float4* pboxes = (const float4*)d_in[1];  // [16,900,4]
    const float4* tboxes = (const float4*)d_in[2];  // [1600,4]
    const int4*   tids4  = (const int4*)d_in[3];    // [1600]
    float4* out4 = (float4*)d_out;                  // [16,900,1600]

    matcher_cost_kernel<<<NBLK, TPB, 0, stream>>>(logits, pboxes, tboxes, tids4, out4);
}